// Round 4
// baseline (1066.981 us; speedup 1.0000x reference)
//
#include <hip/hip_runtime.h>
#include <hip/hip_bf16.h>

#define N_NODES 50000
#define N_EDGES 800000
#define IN_CH   128
#define HID     256
#define OUTC    51

typedef __attribute__((ext_vector_type(8))) short  bf16x8;
typedef __attribute__((ext_vector_type(4))) float  f32x4;
typedef __attribute__((ext_vector_type(4))) unsigned int u32x4;

__device__ __forceinline__ float bf2f(unsigned short u) {
    union { unsigned int i; float f; } v; v.i = ((unsigned int)u) << 16; return v.f;
}
__device__ __forceinline__ unsigned short f2bf(float f) {
    union { float f; unsigned int i; } v; v.f = f;
    unsigned int u = v.i;
    unsigned int r = (u + 0x7fffu + ((u >> 16) & 1u)) >> 16;  // RNE
    return (unsigned short)r;
}
// dtype-agnostic loads: isf=1 -> fp32 source, else bf16 source
__device__ __forceinline__ unsigned short ldbf(const void* p, long i, int isf) {
    return isf ? f2bf(((const float*)p)[i]) : ((const unsigned short*)p)[i];
}
__device__ __forceinline__ float ldf(const void* p, long i, int isf) {
    return isf ? ((const float*)p)[i] : bf2f(((const unsigned short*)p)[i]);
}
// edge_index may be int32 (converted) or raw int64 little-endian
__device__ __forceinline__ void load_edge(const int* __restrict__ ei, int e, int is64,
                                          int* src, int* dst) {
    if (is64) { *src = ei[2 * e]; *dst = ei[2 * (N_EDGES + e)]; }
    else      { *src = ei[e];     *dst = ei[N_EDGES + e]; }
}

// ---------------- zero-init: cursor[50001] + flags[2] ----------------
__global__ __launch_bounds__(256) void zeroinit_kernel(int* __restrict__ cursor, int* __restrict__ flags) {
    int t = blockIdx.x * 256 + threadIdx.x;
    if (t < N_NODES + 1) cursor[t] = 0;
    else if (t < N_NODES + 3) flags[t - (N_NODES + 1)] = 0;
}

// ---------------- dtype probe: flagF=1 if x0 is fp32 ----------------
// bf16 pairs: bits14..7 = lo element's exponent, ~always in [0x60,0x90] for N(0,1).
// fp32: bits14..7 are mantissa bits, uniform -> ~19% hit rate.
__global__ void probe_kernel(const unsigned int* __restrict__ x0w, int* __restrict__ flagF) {
    int lane = threadIdx.x;  // 64 threads
    unsigned int w = x0w[lane];
    unsigned int ex = (w >> 7) & 0xFFu;
    unsigned long long b = __ballot(ex >= 0x60u && ex <= 0x90u);
    if (lane == 0) *flagF = (__popcll(b) >= 48) ? 0 : 1;
}

// ---------------- int64 detect: any nonzero odd word => int32 ----------------
__global__ __launch_bounds__(256) void detect_kernel(const int* __restrict__ ei, int* __restrict__ flagI) {
    int i = blockIdx.x * 256 + threadIdx.x;
    int w = (i < N_EDGES) ? ei[2 * i + 1] : 0;
    unsigned long long b = __ballot(w != 0);
    if (b != 0ull && (threadIdx.x & 63) == 0) atomicOr(flagI, 1);
}

// ---------------- convert x0 + ew to bf16 (copy if already bf16) ----------------
__global__ __launch_bounds__(256) void convert_kernel(const void* __restrict__ x0, const void* __restrict__ ew,
                                                      const int* __restrict__ flagF,
                                                      unsigned short* __restrict__ x0bf,
                                                      unsigned short* __restrict__ ewbf) {
    long t = (long)blockIdx.x * 256 + threadIdx.x;
    int isf = *flagF;
    const long nx = (long)N_NODES * IN_CH;
    if (t < nx) x0bf[t] = ldbf(x0, t, isf);
    else if (t < nx + N_EDGES) ewbf[t - nx] = ldbf(ew, t - nx, isf);
}

// ---------------- weight prep: transpose + concat + bias widen ----------------
__global__ void prep_kernel(const void* __restrict__ w1r, const void* __restrict__ w1x,
                            const void* __restrict__ w2r, const void* __restrict__ w2x,
                            const void* __restrict__ lw,
                            const void* __restrict__ b1h, const void* __restrict__ b2h,
                            const void* __restrict__ lbh, const int* __restrict__ flagF,
                            unsigned short* __restrict__ Bt1, unsigned short* __restrict__ Bt2,
                            unsigned short* __restrict__ Bt3,
                            float* __restrict__ b1, float* __restrict__ b2, float* __restrict__ b3) {
    int isf = *flagF;
    int t = blockIdx.x * 256 + threadIdx.x;
    if (t < 256 * 256) {
        int n = t >> 8, k = t & 255;
        Bt1[n * 256 + k] = (k < 128) ? ldbf(w1r, k * 256 + n, isf) : ldbf(w1x, (k - 128) * 256 + n, isf);
        return;
    }
    t -= 256 * 256;
    if (t < 256 * 512) {
        int n = t >> 9, k = t & 511;
        Bt2[n * 512 + k] = (k < 256) ? ldbf(w2r, k * 256 + n, isf) : ldbf(w2x, (k - 256) * 256 + n, isf);
        return;
    }
    t -= 256 * 512;
    if (t < 64 * 512) {
        int n = t >> 9, k = t & 511;
        Bt3[n * 512 + k] = (n < OUTC) ? ldbf(lw, k * OUTC + n, isf) : (unsigned short)0;
        return;
    }
    t -= 64 * 512;
    if (t < 256) { b1[t] = ldf(b1h, t, isf); return; }
    t -= 256;
    if (t < 256) { b2[t] = ldf(b2h, t, isf); return; }
    t -= 256;
    if (t < 64)  { b3[t] = (t < OUTC) ? ldf(lbh, t, isf) : 0.0f; return; }
}

// ---------------- CSR: histogram ----------------
__global__ __launch_bounds__(256) void hist_kernel(const int* __restrict__ ei, const int* __restrict__ flagI,
                                                   int* __restrict__ cnt) {
    int e = blockIdx.x * 256 + threadIdx.x;
    if (e >= N_EDGES) return;
    int is64 = (*flagI == 0);
    int src, dst; load_edge(ei, e, is64, &src, &dst);
    if ((unsigned)src >= N_NODES || (unsigned)dst >= N_NODES) return;
    atomicAdd(&cnt[dst], 1);
}

// ---------------- CSR: single-block exclusive scan ----------------
__global__ __launch_bounds__(256) void scan_kernel(int* __restrict__ cursor, int* __restrict__ row_ptr) {
    __shared__ int sdata[256];
    __shared__ int s_run;
    int tid = threadIdx.x;
    if (tid == 0) s_run = 0;
    __syncthreads();
    for (int base = 0; base < N_NODES; base += 256) {
        int i = base + tid;
        int v = (i < N_NODES) ? cursor[i] : 0;
        sdata[tid] = v;
        __syncthreads();
        for (int off = 1; off < 256; off <<= 1) {
            int t = (tid >= off) ? sdata[tid - off] : 0;
            __syncthreads();
            sdata[tid] += t;
            __syncthreads();
        }
        int run = s_run;
        int excl = sdata[tid] - v;
        if (i < N_NODES) { row_ptr[i] = run + excl; cursor[i] = run + excl; }
        __syncthreads();
        if (tid == 0) s_run = run + sdata[255];
        __syncthreads();
    }
    if (tid == 0) row_ptr[N_NODES] = s_run;
}

// ---------------- CSR: fill ----------------
__global__ __launch_bounds__(256) void fill_kernel(const int* __restrict__ ei, const unsigned short* __restrict__ ewbf,
                                                   const int* __restrict__ flagI, int* __restrict__ cursor,
                                                   int* __restrict__ col, unsigned short* __restrict__ wgt) {
    int e = blockIdx.x * 256 + threadIdx.x;
    if (e >= N_EDGES) return;
    int is64 = (*flagI == 0);
    int src, dst; load_edge(ei, e, is64, &src, &dst);
    if ((unsigned)src >= N_NODES || (unsigned)dst >= N_NODES) return;
    int pos = atomicAdd(&cursor[dst], 1);
    if ((unsigned)pos < N_EDGES) { col[pos] = src; wgt[pos] = ewbf[e]; }
}

// ---------------- fallback: zero output ----------------
__global__ __launch_bounds__(256) void zout_kernel(unsigned short* __restrict__ out, long n) {
    long t = (long)blockIdx.x * 256 + threadIdx.x;
    if (t < n) out[t] = 0;
}

// ---------------- fused gather-aggregate MFMA GEMM -------------------
// A row r = [ bf16(sum_j w_j * gx[col_j][k]) for k<Kagg | Ax[r][k-Kagg] ]; Kagg % 64 == 0
// Bt: [Ncol x K] bf16. out = relu?(A@Bt^T + bias); head writes fp32 if out_f32.
__global__ __launch_bounds__(256) void gemm_kernel(
    const int* __restrict__ row_ptr, const int* __restrict__ col, const unsigned short* __restrict__ wgt,
    const unsigned short* __restrict__ gx, int gstride, int Kagg,
    const unsigned short* __restrict__ Ax, int lda_x,
    const unsigned short* __restrict__ Bt, int K,
    const float* __restrict__ bias,
    void* __restrict__ out, int ldo, int ocol,
    int M, int realN, int do_relu, const int* __restrict__ flagF, int follow_dtype) {
    __shared__ __align__(16) unsigned short As[64][72];
    __shared__ __align__(16) unsigned short Bs[64][72];
    int tid = threadIdx.x;
    int bm0 = blockIdx.x * 64, bn0 = blockIdx.y * 64;
    int wave = tid >> 6, lane = tid & 63;
    int wm = wave >> 1, wn = wave & 1;
    int quad = lane >> 4, l16 = lane & 15;

    f32x4 acc00 = {0.f,0.f,0.f,0.f}, acc01 = {0.f,0.f,0.f,0.f};
    f32x4 acc10 = {0.f,0.f,0.f,0.f}, acc11 = {0.f,0.f,0.f,0.f};

    for (int k0 = 0; k0 < K; k0 += 64) {
        if (k0 < Kagg) {
            int c16 = tid & 15;
            int rsub = tid >> 4;
#pragma unroll
            for (int p = 0; p < 4; p++) {
                int row = p * 16 + rsub;
                int gr = bm0 + row;
                float a0 = 0.f, a1 = 0.f, a2 = 0.f, a3 = 0.f;
                if (gr < M) {
                    int js = row_ptr[gr], je = row_ptr[gr + 1];
                    if (js < 0) js = 0;
                    if (je > N_EDGES) je = N_EDGES;
                    const unsigned short* gxk = gx + k0 + c16 * 4;
                    int j = js;
                    for (; j + 4 <= je; j += 4) {
                        int s0 = col[j], s1 = col[j+1], s2 = col[j+2], s3 = col[j+3];
                        float w0 = bf2f(wgt[j]),   w1 = bf2f(wgt[j+1]);
                        float w2 = bf2f(wgt[j+2]), w3 = bf2f(wgt[j+3]);
                        ushort4 q0 = *(const ushort4*)(gxk + (long)s0 * gstride);
                        ushort4 q1 = *(const ushort4*)(gxk + (long)s1 * gstride);
                        ushort4 q2 = *(const ushort4*)(gxk + (long)s2 * gstride);
                        ushort4 q3 = *(const ushort4*)(gxk + (long)s3 * gstride);
                        a0 += w0 * bf2f(q0.x) + w1 * bf2f(q1.x) + w2 * bf2f(q2.x) + w3 * bf2f(q3.x);
                        a1 += w0 * bf2f(q0.y) + w1 * bf2f(q1.y) + w2 * bf2f(q2.y) + w3 * bf2f(q3.y);
                        a2 += w0 * bf2f(q0.z) + w1 * bf2f(q1.z) + w2 * bf2f(q2.z) + w3 * bf2f(q3.z);
                        a3 += w0 * bf2f(q0.w) + w1 * bf2f(q1.w) + w2 * bf2f(q2.w) + w3 * bf2f(q3.w);
                    }
                    for (; j < je; j++) {
                        int s0 = col[j];
                        float w0 = bf2f(wgt[j]);
                        ushort4 q0 = *(const ushort4*)(gxk + (long)s0 * gstride);
                        a0 += w0 * bf2f(q0.x); a1 += w0 * bf2f(q0.y);
                        a2 += w0 * bf2f(q0.z); a3 += w0 * bf2f(q0.w);
                    }
                }
                uint2 pk;
                pk.x = (unsigned int)f2bf(a0) | ((unsigned int)f2bf(a1) << 16);
                pk.y = (unsigned int)f2bf(a2) | ((unsigned int)f2bf(a3) << 16);
                *(uint2*)&As[row][c16 * 4] = pk;
            }
        } else {
#pragma unroll
            for (int i = 0; i < 2; i++) {
                int c = tid + i * 256;
                int row = c >> 3, ko = (c & 7) * 8;
                int gr = bm0 + row;
                u32x4 v = {0u, 0u, 0u, 0u};
                if (gr < M) v = *(const u32x4*)(Ax + (long)gr * lda_x + (k0 - Kagg) + ko);
                *(u32x4*)&As[row][ko] = v;
            }
        }
#pragma unroll
        for (int i = 0; i < 2; i++) {
            int c = tid + i * 256;
            int row = c >> 3, ko = (c & 7) * 8;
            u32x4 v = *(const u32x4*)(Bt + (long)(bn0 + row) * K + k0 + ko);
            *(u32x4*)&Bs[row][ko] = v;
        }
        __syncthreads();
#pragma unroll
        for (int kc = 0; kc < 64; kc += 32) {
            bf16x8 a0 = *(const bf16x8*)&As[wm * 32 + l16][kc + quad * 8];
            bf16x8 a1 = *(const bf16x8*)&As[wm * 32 + 16 + l16][kc + quad * 8];
            bf16x8 b0 = *(const bf16x8*)&Bs[wn * 32 + l16][kc + quad * 8];
            bf16x8 b1 = *(const bf16x8*)&Bs[wn * 32 + 16 + l16][kc + quad * 8];
            acc00 = __builtin_amdgcn_mfma_f32_16x16x32_bf16(a0, b0, acc00, 0, 0, 0);
            acc01 = __builtin_amdgcn_mfma_f32_16x16x32_bf16(a0, b1, acc01, 0, 0, 0);
            acc10 = __builtin_amdgcn_mfma_f32_16x16x32_bf16(a1, b0, acc10, 0, 0, 0);
            acc11 = __builtin_amdgcn_mfma_f32_16x16x32_bf16(a1, b1, acc11, 0, 0, 0);
        }
        __syncthreads();
    }

    int out_f32 = follow_dtype ? (*flagF) : 0;
#pragma unroll
    for (int mt = 0; mt < 2; mt++) {
#pragma unroll
        for (int nt = 0; nt < 2; nt++) {
            f32x4 a = (mt == 0) ? (nt == 0 ? acc00 : acc01) : (nt == 0 ? acc10 : acc11);
            int colI = bn0 + wn * 32 + nt * 16 + l16;
            float bv = bias[colI];
#pragma unroll
            for (int r = 0; r < 4; r++) {
                int row = bm0 + wm * 32 + mt * 16 + quad * 4 + r;
                if (row < M && colI < realN) {
                    float v = a[r] + bv;
                    if (do_relu) v = v > 0.f ? v : 0.f;
                    long idx = (long)row * ldo + ocol + colI;
                    if (out_f32) ((float*)out)[idx] = v;
                    else ((unsigned short*)out)[idx] = f2bf(v);
                }
            }
        }
    }
}

extern "C" void kernel_launch(void* const* d_in, const int* in_sizes, int n_in,
                              void* d_out, int out_size, void* d_ws, size_t ws_size,
                              hipStream_t stream) {
    const void* x0  = d_in[0];
    const int*  ei  = (const int*)d_in[1];
    const void* ew  = d_in[2];
    const void* w1r = d_in[3];
    const void* b1h = d_in[4];
    const void* w1x = d_in[5];
    const void* w2r = d_in[6];
    const void* b2h = d_in[7];
    const void* w2x = d_in[8];
    const void* lw  = d_in[9];
    const void* lbh = d_in[10];

    // ---- workspace layout (byte offsets) ----
    char* ws = (char*)d_ws;
    unsigned short* X12     = (unsigned short*)(ws);             // 51,200,000
    int*            colA    = (int*)(ws + 51200000);             //  3,200,000
    unsigned short* wgtA    = (unsigned short*)(ws + 54400000);  //  1,600,000
    int*            row_ptr = (int*)(ws + 56000000);             //    200,064
    int*            cursor  = (int*)(ws + 56200064);             //    200,064
    unsigned short* Bt1     = (unsigned short*)(ws + 56400128);  //    131,072
    unsigned short* Bt2     = (unsigned short*)(ws + 56531200);  //    262,144
    unsigned short* Bt3     = (unsigned short*)(ws + 56793344);  //     65,536
    float*          b1      = (float*)(ws + 56858880);           //      1,024
    float*          b2      = (float*)(ws + 56859904);           //      1,024
    float*          b3      = (float*)(ws + 56860928);           //        256
    int*            flags   = (int*)(ws + 56861184);             //        256
    unsigned short* x0bf    = (unsigned short*)(ws + 56861440);  // 12,800,000
    unsigned short* ewbf    = (unsigned short*)(ws + 69661440);  //  1,600,000
    const size_t NEED_FULL   = 71261440;
    const size_t NEED_NOCONV = 56861440;

    if (ws_size < NEED_NOCONV) {
        // cannot run: emit zeros (diagnostic: absmax will be exactly max|ref|)
        long n = (long)N_NODES * OUTC;
        zout_kernel<<<(int)((n + 255) / 256), 256, 0, stream>>>((unsigned short*)d_out, n);
        return;
    }
    int do_conv = (ws_size >= NEED_FULL) ? 1 : 0;

    int* flagF = flags + 0;
    int* flagI = flags + 1;

    zeroinit_kernel<<<(N_NODES + 3 + 255) / 256, 256, 0, stream>>>(cursor, flags);
    probe_kernel<<<1, 64, 0, stream>>>((const unsigned int*)x0, flagF);
    int eblocks = (N_EDGES + 255) / 256;
    detect_kernel<<<eblocks, 256, 0, stream>>>(ei, flagI);

    const unsigned short* x0b;
    const unsigned short* ewb;
    if (do_conv) {
        long nconv = (long)N_NODES * IN_CH + N_EDGES;
        convert_kernel<<<(int)((nconv + 255) / 256), 256, 0, stream>>>(x0, ew, flagF, x0bf, ewbf);
        x0b = x0bf; ewb = ewbf;
    } else {
        x0b = (const unsigned short*)x0; ewb = (const unsigned short*)ew;
    }

    {
        int total = 256 * 256 + 256 * 512 + 64 * 512 + 256 + 256 + 64;
        prep_kernel<<<(total + 255) / 256, 256, 0, stream>>>(w1r, w1x, w2r, w2x, lw, b1h, b2h, lbh,
                                                             flagF, Bt1, Bt2, Bt3, b1, b2, b3);
    }

    hist_kernel<<<eblocks, 256, 0, stream>>>(ei, flagI, cursor);
    scan_kernel<<<1, 256, 0, stream>>>(cursor, row_ptr);
    fill_kernel<<<eblocks, 256, 0, stream>>>(ei, ewb, flagI, cursor, colA, wgtA);

    int mblocks = (N_NODES + 63) / 64;  // 782
    // layer 1: [aggr(x0) | x0] (K=256) @ Bt1 -> x1 (X12 cols 0..255), relu
    gemm_kernel<<<dim3(mblocks, 4), 256, 0, stream>>>(row_ptr, colA, wgtA,
                                                      x0b, IN_CH, 128,
                                                      x0b, IN_CH, Bt1, 256, b1,
                                                      X12, 512, 0, N_NODES, 256, 1, flagF, 0);
    // layer 2: [aggr(x1) | x1] (K=512) @ Bt2 -> x2 (X12 cols 256..511), relu
    gemm_kernel<<<dim3(mblocks, 4), 256, 0, stream>>>(row_ptr, colA, wgtA,
                                                      X12, 512, 256,
                                                      X12, 512, Bt2, 512, b2,
                                                      X12, 512, 256, N_NODES, 256, 1, flagF, 0);
    // head: [x1|x2] (K=512) @ Bt3 -> out (51 cols); dtype follows input dtype
    gemm_kernel<<<dim3(mblocks, 1), 256, 0, stream>>>(row_ptr, colA, wgtA,
                                                      X12, 512, 0,
                                                      X12, 512, Bt3, 512, b3,
                                                      d_out, OUTC, 0, N_NODES, OUTC, 0, flagF, 1);
}

// Round 5
// 530.640 us; speedup vs baseline: 2.0107x; 2.0107x over previous
//
#include <hip/hip_runtime.h>
#include <hip/hip_bf16.h>

#define N_NODES 50000
#define N_EDGES 800000
#define IN_CH   128
#define HID     256
#define OUTC    51

typedef __attribute__((ext_vector_type(8))) short  bf16x8;
typedef __attribute__((ext_vector_type(4))) float  f32x4;
typedef __attribute__((ext_vector_type(4))) unsigned int u32x4;

__device__ __forceinline__ float bf2f(unsigned short u) {
    union { unsigned int i; float f; } v; v.i = ((unsigned int)u) << 16; return v.f;
}
__device__ __forceinline__ unsigned short f2bf(float f) {
    union { float f; unsigned int i; } v; v.f = f;
    unsigned int u = v.i;
    unsigned int r = (u + 0x7fffu + ((u >> 16) & 1u)) >> 16;  // RNE
    return (unsigned short)r;
}
__device__ __forceinline__ unsigned short ldbf(const void* p, long i, int isf) {
    return isf ? f2bf(((const float*)p)[i]) : ((const unsigned short*)p)[i];
}
__device__ __forceinline__ float ldf(const void* p, long i, int isf) {
    return isf ? ((const float*)p)[i] : bf2f(((const unsigned short*)p)[i]);
}
__device__ __forceinline__ void load_edge(const int* __restrict__ ei, int e, int is64,
                                          int* src, int* dst) {
    if (is64) { *src = ei[2 * e]; *dst = ei[2 * (N_EDGES + e)]; }
    else      { *src = ei[e];     *dst = ei[N_EDGES + e]; }
}

// ---------------- zero-init: cursor[50001] + flags[2] ----------------
__global__ __launch_bounds__(256) void zeroinit_kernel(int* __restrict__ cursor, int* __restrict__ flags) {
    int t = blockIdx.x * 256 + threadIdx.x;
    if (t < N_NODES + 1) cursor[t] = 0;
    else if (t < N_NODES + 3) flags[t - (N_NODES + 1)] = 0;
}

// ---------------- dtype probe: flagF=1 if float inputs are fp32 ----------------
__global__ void probe_kernel(const unsigned int* __restrict__ x0w, int* __restrict__ flagF) {
    int lane = threadIdx.x;  // 64 threads
    unsigned int w = x0w[lane];
    unsigned int ex = (w >> 7) & 0xFFu;
    unsigned long long b = __ballot(ex >= 0x60u && ex <= 0x90u);
    if (lane == 0) *flagF = (__popcll(b) >= 48) ? 0 : 1;
}

// ---------------- int64 detect ----------------
__global__ __launch_bounds__(256) void detect_kernel(const int* __restrict__ ei, int* __restrict__ flagI) {
    int i = blockIdx.x * 256 + threadIdx.x;
    int w = (i < N_EDGES) ? ei[2 * i + 1] : 0;
    unsigned long long b = __ballot(w != 0);
    if (b != 0ull && (threadIdx.x & 63) == 0) atomicOr(flagI, 1);
}

// ---------------- convert x0 to bf16 (copy if already bf16) ----------------
__global__ __launch_bounds__(256) void convert_kernel(const void* __restrict__ x0, const int* __restrict__ flagF,
                                                      unsigned short* __restrict__ x0bf) {
    long t = (long)blockIdx.x * 256 + threadIdx.x;
    int isf = *flagF;
    if (t < (long)N_NODES * IN_CH) x0bf[t] = ldbf(x0, t, isf);
}

// ---------------- weight prep ----------------
__global__ void prep_kernel(const void* __restrict__ w1r, const void* __restrict__ w1x,
                            const void* __restrict__ w2r, const void* __restrict__ w2x,
                            const void* __restrict__ lw,
                            const void* __restrict__ b1h, const void* __restrict__ b2h,
                            const void* __restrict__ lbh, const int* __restrict__ flagF,
                            unsigned short* __restrict__ Bt1, unsigned short* __restrict__ Bt2,
                            unsigned short* __restrict__ Bt3,
                            float* __restrict__ b1, float* __restrict__ b2, float* __restrict__ b3) {
    int isf = *flagF;
    int t = blockIdx.x * 256 + threadIdx.x;
    if (t < 256 * 256) {
        int n = t >> 8, k = t & 255;
        Bt1[n * 256 + k] = (k < 128) ? ldbf(w1r, k * 256 + n, isf) : ldbf(w1x, (k - 128) * 256 + n, isf);
        return;
    }
    t -= 256 * 256;
    if (t < 256 * 512) {
        int n = t >> 9, k = t & 511;
        Bt2[n * 512 + k] = (k < 256) ? ldbf(w2r, k * 256 + n, isf) : ldbf(w2x, (k - 256) * 256 + n, isf);
        return;
    }
    t -= 256 * 512;
    if (t < 64 * 512) {
        int n = t >> 9, k = t & 511;
        Bt3[n * 512 + k] = (n < OUTC) ? ldbf(lw, k * OUTC + n, isf) : (unsigned short)0;
        return;
    }
    t -= 64 * 512;
    if (t < 256) { b1[t] = ldf(b1h, t, isf); return; }
    t -= 256;
    if (t < 256) { b2[t] = ldf(b2h, t, isf); return; }
    t -= 256;
    if (t < 64)  { b3[t] = (t < OUTC) ? ldf(lbh, t, isf) : 0.0f; return; }
}

// ---------------- CSR: histogram ----------------
__global__ __launch_bounds__(256) void hist_kernel(const int* __restrict__ ei, const int* __restrict__ flagI,
                                                   int* __restrict__ cnt) {
    int e = blockIdx.x * 256 + threadIdx.x;
    if (e >= N_EDGES) return;
    int is64 = (*flagI == 0);
    int src, dst; load_edge(ei, e, is64, &src, &dst);
    if ((unsigned)src >= N_NODES || (unsigned)dst >= N_NODES) return;
    atomicAdd(&cnt[dst], 1);
}

// ---------------- 3-phase exclusive scan ----------------
__global__ __launch_bounds__(256) void scanA_kernel(const int* __restrict__ cnt, int* __restrict__ rp,
                                                    int* __restrict__ bsum) {
    __shared__ int sd[256];
    int tid = threadIdx.x;
    int i = blockIdx.x * 256 + tid;
    int v = (i < N_NODES) ? cnt[i] : 0;
    sd[tid] = v;
    __syncthreads();
    for (int off = 1; off < 256; off <<= 1) {
        int t = (tid >= off) ? sd[tid - off] : 0;
        __syncthreads();
        sd[tid] += t;
        __syncthreads();
    }
    if (i < N_NODES) rp[i] = sd[tid] - v;
    if (tid == 255) bsum[blockIdx.x] = sd[255];
}
__global__ __launch_bounds__(256) void scanB_kernel(int* __restrict__ bsum, int nB, int* __restrict__ rpN) {
    __shared__ int sd[256];
    int tid = threadIdx.x;
    int v = (tid < nB) ? bsum[tid] : 0;
    sd[tid] = v;
    __syncthreads();
    for (int off = 1; off < 256; off <<= 1) {
        int t = (tid >= off) ? sd[tid - off] : 0;
        __syncthreads();
        sd[tid] += t;
        __syncthreads();
    }
    if (tid < nB) bsum[tid] = sd[tid] - v;
    if (tid == 255) *rpN = sd[255];
}
__global__ __launch_bounds__(256) void scanC_kernel(int* __restrict__ rp, const int* __restrict__ bsum,
                                                    int* __restrict__ cursor) {
    int i = blockIdx.x * 256 + threadIdx.x;
    if (i < N_NODES) {
        int v = rp[i] + bsum[blockIdx.x];
        rp[i] = v;
        cursor[i] = v;
    }
}

// ---------------- CSR: fill (converts weight to bf16 inline) ----------------
__global__ __launch_bounds__(256) void fill_kernel(const int* __restrict__ ei, const void* __restrict__ ew,
                                                   const int* __restrict__ flagI, const int* __restrict__ flagF,
                                                   int* __restrict__ cursor,
                                                   int* __restrict__ col, unsigned short* __restrict__ wgt) {
    int e = blockIdx.x * 256 + threadIdx.x;
    if (e >= N_EDGES) return;
    int is64 = (*flagI == 0);
    int src, dst; load_edge(ei, e, is64, &src, &dst);
    if ((unsigned)src >= N_NODES || (unsigned)dst >= N_NODES) return;
    int pos = atomicAdd(&cursor[dst], 1);
    if ((unsigned)pos < N_EDGES) { col[pos] = src; wgt[pos] = ldbf(ew, e, *flagF); }
}

// ---------------- fallback: zero output ----------------
__global__ __launch_bounds__(256) void zout_kernel(unsigned short* __restrict__ out, long n) {
    long t = (long)blockIdx.x * 256 + threadIdx.x;
    if (t < n) out[t] = 0;
}

// ---------------- agg1: X12[r][256+c] = bf16(sum_j w_j * x0[col_j][c]), c<128 ----------------
// one wave per node, lane handles 2 channels (uint = 2 bf16)
__global__ __launch_bounds__(256) void agg1_kernel(const unsigned short* __restrict__ x0b,
                                                   const int* __restrict__ rp, const int* __restrict__ col,
                                                   const unsigned short* __restrict__ wgt,
                                                   unsigned short* __restrict__ X12) {
    int r = blockIdx.x * 4 + (threadIdx.x >> 6);
    if (r >= N_NODES) return;
    int lane = threadIdx.x & 63;
    int js = rp[r], je = rp[r + 1];
    if (js < 0) js = 0;
    if (je > N_EDGES) je = N_EDGES;
    const unsigned int* xw = (const unsigned int*)x0b;  // 64 uints per row
    float a0 = 0.f, a1 = 0.f;
    int j = js;
    for (; j + 4 <= je; j += 4) {
        int s0 = col[j], s1 = col[j+1], s2 = col[j+2], s3 = col[j+3];
        float w0 = bf2f(wgt[j]),   w1 = bf2f(wgt[j+1]);
        float w2 = bf2f(wgt[j+2]), w3 = bf2f(wgt[j+3]);
        unsigned int p0 = xw[(long)s0 * 64 + lane];
        unsigned int p1 = xw[(long)s1 * 64 + lane];
        unsigned int p2 = xw[(long)s2 * 64 + lane];
        unsigned int p3 = xw[(long)s3 * 64 + lane];
        a0 += w0 * bf2f((unsigned short)p0) + w1 * bf2f((unsigned short)p1)
            + w2 * bf2f((unsigned short)p2) + w3 * bf2f((unsigned short)p3);
        a1 += w0 * bf2f((unsigned short)(p0 >> 16)) + w1 * bf2f((unsigned short)(p1 >> 16))
            + w2 * bf2f((unsigned short)(p2 >> 16)) + w3 * bf2f((unsigned short)(p3 >> 16));
    }
    for (; j < je; j++) {
        int s0 = col[j];
        float w0 = bf2f(wgt[j]);
        unsigned int p0 = xw[(long)s0 * 64 + lane];
        a0 += w0 * bf2f((unsigned short)p0);
        a1 += w0 * bf2f((unsigned short)(p0 >> 16));
    }
    unsigned int pk = (unsigned int)f2bf(a0) | ((unsigned int)f2bf(a1) << 16);
    *(unsigned int*)&X12[(long)r * 512 + 256 + lane * 2] = pk;
}

// ---------------- agg2: X12[r][256+c] = bf16(sum_j w_j * x1[col_j][c]), c<256 ----------------
// x1 = X12 cols 0..255; writes cols 256..511 (overwrites agg1, after gemm1)
__global__ __launch_bounds__(256) void agg2_kernel(const int* __restrict__ rp, const int* __restrict__ col,
                                                   const unsigned short* __restrict__ wgt,
                                                   unsigned short* __restrict__ X12) {
    int r = blockIdx.x * 4 + (threadIdx.x >> 6);
    if (r >= N_NODES) return;
    int lane = threadIdx.x & 63;
    int js = rp[r], je = rp[r + 1];
    if (js < 0) js = 0;
    if (je > N_EDGES) je = N_EDGES;
    float a0 = 0.f, a1 = 0.f, a2 = 0.f, a3 = 0.f;
    int j = js;
    for (; j + 4 <= je; j += 4) {
        int s0 = col[j], s1 = col[j+1], s2 = col[j+2], s3 = col[j+3];
        float w0 = bf2f(wgt[j]),   w1 = bf2f(wgt[j+1]);
        float w2 = bf2f(wgt[j+2]), w3 = bf2f(wgt[j+3]);
        ushort4 q0 = *(const ushort4*)(X12 + (long)s0 * 512 + lane * 4);
        ushort4 q1 = *(const ushort4*)(X12 + (long)s1 * 512 + lane * 4);
        ushort4 q2 = *(const ushort4*)(X12 + (long)s2 * 512 + lane * 4);
        ushort4 q3 = *(const ushort4*)(X12 + (long)s3 * 512 + lane * 4);
        a0 += w0 * bf2f(q0.x) + w1 * bf2f(q1.x) + w2 * bf2f(q2.x) + w3 * bf2f(q3.x);
        a1 += w0 * bf2f(q0.y) + w1 * bf2f(q1.y) + w2 * bf2f(q2.y) + w3 * bf2f(q3.y);
        a2 += w0 * bf2f(q0.z) + w1 * bf2f(q1.z) + w2 * bf2f(q2.z) + w3 * bf2f(q3.z);
        a3 += w0 * bf2f(q0.w) + w1 * bf2f(q1.w) + w2 * bf2f(q2.w) + w3 * bf2f(q3.w);
    }
    for (; j < je; j++) {
        int s0 = col[j];
        float w0 = bf2f(wgt[j]);
        ushort4 q0 = *(const ushort4*)(X12 + (long)s0 * 512 + lane * 4);
        a0 += w0 * bf2f(q0.x); a1 += w0 * bf2f(q0.y);
        a2 += w0 * bf2f(q0.z); a3 += w0 * bf2f(q0.w);
    }
    uint2 pk;
    pk.x = (unsigned int)f2bf(a0) | ((unsigned int)f2bf(a1) << 16);
    pk.y = (unsigned int)f2bf(a2) | ((unsigned int)f2bf(a3) << 16);
    *(uint2*)&X12[(long)r * 512 + 256 + lane * 4] = pk;
}

// ---------------- MFMA GEMM, full-width (grid y=1) -------------------
// A row r = [ Aagg[r][0..Kagg) | Ax[r][0..K-Kagg) ]  (both bf16, strides lda_agg/lda_x)
// Bt: [TN*32 x K] bf16. out = relu?(A@Bt^T + bias). Ncol = TN*32.
// 4 waves 2x2: wave covers 32 rows x TN*16 cols. Row-partitioned by blockIdx.x,
// so per-row output writes are safe even when out aliases Aagg (reads precede
// the final barrier; epilogue writes follow it).
template<int TN>
__global__ __launch_bounds__(256) void gemm_kernel(
    const unsigned short* __restrict__ Aagg, int lda_agg, int Kagg,
    const unsigned short* __restrict__ Ax, int lda_x,
    const unsigned short* __restrict__ Bt, int K,
    const float* __restrict__ bias,
    void* __restrict__ out, int ldo, int ocol,
    int M, int realN, int do_relu, const int* __restrict__ flagF, int follow_dtype) {
    __shared__ __align__(16) unsigned short As[64][72];
    __shared__ __align__(16) unsigned short Bs[TN * 32][72];
    int tid = threadIdx.x;
    int bm0 = blockIdx.x * 64;
    int wave = tid >> 6, lane = tid & 63;
    int wm = wave >> 1, wn = wave & 1;
    int quad = lane >> 4, l16 = lane & 15;

    f32x4 acc[2][TN];
#pragma unroll
    for (int mt = 0; mt < 2; mt++)
#pragma unroll
        for (int nt = 0; nt < TN; nt++) acc[mt][nt] = (f32x4){0.f, 0.f, 0.f, 0.f};

    for (int k0 = 0; k0 < K; k0 += 64) {
        const unsigned short* srcp;
        int stride, koff;
        if (k0 < Kagg) { srcp = Aagg; stride = lda_agg; koff = k0; }
        else           { srcp = Ax;   stride = lda_x;   koff = k0 - Kagg; }
#pragma unroll
        for (int i = 0; i < 2; i++) {
            int c = tid + i * 256;
            int row = c >> 3, ko = (c & 7) * 8;
            int gr = bm0 + row;
            if (gr >= M) gr = M - 1;  // clamp: dup rows, writes guarded
            u32x4 v = *(const u32x4*)(srcp + (long)gr * stride + koff + ko);
            *(u32x4*)&As[row][ko] = v;
        }
#pragma unroll
        for (int p = 0; p < TN; p++) {
            int c = p * 256 + tid;
            int row = c >> 3, ko = (c & 7) * 8;
            u32x4 v = *(const u32x4*)(Bt + (long)row * K + k0 + ko);
            *(u32x4*)&Bs[row][ko] = v;
        }
        __syncthreads();
#pragma unroll
        for (int kc = 0; kc < 64; kc += 32) {
            bf16x8 a0 = *(const bf16x8*)&As[wm * 32 + l16][kc + quad * 8];
            bf16x8 a1 = *(const bf16x8*)&As[wm * 32 + 16 + l16][kc + quad * 8];
#pragma unroll
            for (int nt = 0; nt < TN; nt++) {
                bf16x8 b = *(const bf16x8*)&Bs[wn * (TN * 16) + nt * 16 + l16][kc + quad * 8];
                acc[0][nt] = __builtin_amdgcn_mfma_f32_16x16x32_bf16(a0, b, acc[0][nt], 0, 0, 0);
                acc[1][nt] = __builtin_amdgcn_mfma_f32_16x16x32_bf16(a1, b, acc[1][nt], 0, 0, 0);
            }
        }
        __syncthreads();
    }

    int out_f32 = follow_dtype ? (*flagF) : 0;
#pragma unroll
    for (int mt = 0; mt < 2; mt++) {
#pragma unroll
        for (int nt = 0; nt < TN; nt++) {
            f32x4 a = acc[mt][nt];
            int colI = wn * (TN * 16) + nt * 16 + l16;
            float bv = bias[colI];
#pragma unroll
            for (int r = 0; r < 4; r++) {
                int row = bm0 + wm * 32 + mt * 16 + quad * 4 + r;
                if (row < M && colI < realN) {
                    float v = a[r] + bv;
                    if (do_relu) v = v > 0.f ? v : 0.f;
                    long idx = (long)row * ldo + ocol + colI;
                    if (out_f32) ((float*)out)[idx] = v;
                    else ((unsigned short*)out)[idx] = f2bf(v);
                }
            }
        }
    }
}

extern "C" void kernel_launch(void* const* d_in, const int* in_sizes, int n_in,
                              void* d_out, int out_size, void* d_ws, size_t ws_size,
                              hipStream_t stream) {
    const void* x0  = d_in[0];
    const int*  ei  = (const int*)d_in[1];
    const void* ew  = d_in[2];
    const void* w1r = d_in[3];
    const void* b1h = d_in[4];
    const void* w1x = d_in[5];
    const void* w2r = d_in[6];
    const void* b2h = d_in[7];
    const void* w2x = d_in[8];
    const void* lw  = d_in[9];
    const void* lbh = d_in[10];

    // ---- workspace layout ----
    char* ws = (char*)d_ws;
    unsigned short* X12     = (unsigned short*)(ws);             // 51,200,000  [N x 512]
    int*            colA    = (int*)(ws + 51200000);             //  3,200,000
    unsigned short* wgtA    = (unsigned short*)(ws + 54400000);  //  1,600,000
    int*            row_ptr = (int*)(ws + 56000000);             //    200,064
    int*            cursor  = (int*)(ws + 56200064);             //    200,064
    unsigned short* Bt1     = (unsigned short*)(ws + 56400128);  //    131,072
    unsigned short* Bt2     = (unsigned short*)(ws + 56531200);  //    262,144
    unsigned short* Bt3     = (unsigned short*)(ws + 56793344);  //     65,536
    float*          b1      = (float*)(ws + 56858880);           //      1,024
    float*          b2      = (float*)(ws + 56859904);           //      1,024
    float*          b3      = (float*)(ws + 56860928);           //        256
    int*            flags   = (int*)(ws + 56861184);             //         64
    int*            bsum    = (int*)(ws + 56861248);             //      1,024
    unsigned short* x0bf    = (unsigned short*)(ws + 56862272);  // 12,800,000
    const size_t NEED_FULL   = 69662272;
    const size_t NEED_NOCONV = 56862272;

    if (ws_size < NEED_NOCONV) {
        long n = (long)N_NODES * OUTC;
        zout_kernel<<<(int)((n + 255) / 256), 256, 0, stream>>>((unsigned short*)d_out, n);
        return;
    }
    int do_conv = (ws_size >= NEED_FULL) ? 1 : 0;

    int* flagF = flags + 0;
    int* flagI = flags + 1;

    zeroinit_kernel<<<(N_NODES + 3 + 255) / 256, 256, 0, stream>>>(cursor, flags);
    probe_kernel<<<1, 64, 0, stream>>>((const unsigned int*)x0, flagF);
    int eblocks = (N_EDGES + 255) / 256;
    detect_kernel<<<eblocks, 256, 0, stream>>>(ei, flagI);

    const unsigned short* x0b;
    if (do_conv) {
        long nconv = (long)N_NODES * IN_CH;
        convert_kernel<<<(int)((nconv + 255) / 256), 256, 0, stream>>>(x0, flagF, x0bf);
        x0b = x0bf;
    } else {
        x0b = (const unsigned short*)x0;
    }

    {
        int total = 256 * 256 + 256 * 512 + 64 * 512 + 256 + 256 + 64;
        prep_kernel<<<(total + 255) / 256, 256, 0, stream>>>(w1r, w1x, w2r, w2x, lw, b1h, b2h, lbh,
                                                             flagF, Bt1, Bt2, Bt3, b1, b2, b3);
    }

    // CSR build
    int nblk = (N_NODES + 255) / 256;  // 196
    hist_kernel<<<eblocks, 256, 0, stream>>>(ei, flagI, cursor);
    scanA_kernel<<<nblk, 256, 0, stream>>>(cursor, row_ptr, bsum);
    scanB_kernel<<<1, 256, 0, stream>>>(bsum, nblk, &row_ptr[N_NODES]);
    scanC_kernel<<<nblk, 256, 0, stream>>>(row_ptr, bsum, cursor);
    fill_kernel<<<eblocks, 256, 0, stream>>>(ei, ew, flagI, flagF, cursor, colA, wgtA);

    int mblocks = (N_NODES + 63) / 64;  // 782
    int ablocks = (N_NODES + 3) / 4;    // 12500

    // layer 1: agg1 -> X12 cols 256..383; gemm1: [agg1|x0] @ Bt1 -> x1 (cols 0..255)
    agg1_kernel<<<ablocks, 256, 0, stream>>>(x0b, row_ptr, colA, wgtA, X12);
    gemm_kernel<8><<<dim3(mblocks, 1), 256, 0, stream>>>(X12 + 256, 512, 128,
                                                         x0b, IN_CH, Bt1, 256, b1,
                                                         X12, 512, 0, N_NODES, 256, 1, flagF, 0);
    // layer 2: agg2 -> X12 cols 256..511; gemm2: [agg2|x1] @ Bt2 -> x2 (cols 256..511, overwrites agg2 per-row)
    agg2_kernel<<<ablocks, 256, 0, stream>>>(row_ptr, colA, wgtA, X12);
    gemm_kernel<8><<<dim3(mblocks, 1), 256, 0, stream>>>(X12 + 256, 512, 256,
                                                         X12, 512, Bt2, 512, b2,
                                                         X12, 512, 256, N_NODES, 256, 1, flagF, 0);
    // head: [x1|x2] @ Bt3 -> out
    gemm_kernel<2><<<dim3(mblocks, 1), 256, 0, stream>>>(X12 + 256, 512, 0,
                                                         X12, 512, Bt3, 512, b3,
                                                         d_out, OUTC, 0, N_NODES, OUTC, 0, flagF, 1);
}

// Round 6
// 389.013 us; speedup vs baseline: 2.7428x; 1.3641x over previous
//
#include <hip/hip_runtime.h>
#include <hip/hip_bf16.h>

#define N_NODES 50000
#define N_EDGES 800000
#define IN_CH   128
#define HID     256
#define OUTC    51

typedef __attribute__((ext_vector_type(8))) short  bf16x8;
typedef __attribute__((ext_vector_type(4))) float  f32x4;
typedef __attribute__((ext_vector_type(4))) unsigned int u32x4;

__device__ __forceinline__ float bf2f(unsigned short u) {
    union { unsigned int i; float f; } v; v.i = ((unsigned int)u) << 16; return v.f;
}
__device__ __forceinline__ unsigned short f2bf(float f) {
    union { float f; unsigned int i; } v; v.f = f;
    unsigned int u = v.i;
    unsigned int r = (u + 0x7fffu + ((u >> 16) & 1u)) >> 16;  // RNE
    return (unsigned short)r;
}
__device__ __forceinline__ unsigned short ldbf(const void* p, long i, int isf) {
    return isf ? f2bf(((const float*)p)[i]) : ((const unsigned short*)p)[i];
}
__device__ __forceinline__ float ldf(const void* p, long i, int isf) {
    return isf ? ((const float*)p)[i] : bf2f(((const unsigned short*)p)[i]);
}
__device__ __forceinline__ void load_edge(const int* __restrict__ ei, int e, int is64,
                                          int* src, int* dst) {
    if (is64) { *src = ei[2 * e]; *dst = ei[2 * (N_EDGES + e)]; }
    else      { *src = ei[e];     *dst = ei[N_EDGES + e]; }
}

// ---------------- zero-init: cursor[50001] + flags[2] ----------------
__global__ __launch_bounds__(256) void zeroinit_kernel(int* __restrict__ cursor, int* __restrict__ flags) {
    int t = blockIdx.x * 256 + threadIdx.x;
    if (t < N_NODES + 1) cursor[t] = 0;
    else if (t < N_NODES + 3) flags[t - (N_NODES + 1)] = 0;
}

// ---------------- dtype probe: flagF=1 if float inputs are fp32 ----------------
__global__ void probe_kernel(const unsigned int* __restrict__ x0w, int* __restrict__ flagF) {
    int lane = threadIdx.x;  // 64 threads
    unsigned int w = x0w[lane];
    unsigned int ex = (w >> 7) & 0xFFu;
    unsigned long long b = __ballot(ex >= 0x60u && ex <= 0x90u);
    if (lane == 0) *flagF = (__popcll(b) >= 48) ? 0 : 1;
}

// ---------------- int64 detect: single block, 2048 strided samples ----------------
// int64 data => ALL odd words zero. int32 data => samples are src/dst values,
// P(all 2048 samples == 0) ~ (2e-5)^2048 ~ 0. One plain store, no atomics.
__global__ __launch_bounds__(256) void detect_kernel(const int* __restrict__ ei, int* __restrict__ flagI) {
    __shared__ int any;
    if (threadIdx.x == 0) any = 0;
    __syncthreads();
    int acc = 0;
    // 256 threads x 8 samples, strided across the first E odd words
    for (int s = 0; s < 8; s++) {
        int i = (threadIdx.x * 8 + s) * (N_EDGES / 2048);  // < N_EDGES
        acc |= ei[2 * i + 1];
    }
    if (acc != 0) any = 1;  // benign race, same value
    __syncthreads();
    if (threadIdx.x == 0) *flagI = any;
}

// ---------------- convert x0 to bf16 (copy if already bf16) ----------------
__global__ __launch_bounds__(256) void convert_kernel(const void* __restrict__ x0, const int* __restrict__ flagF,
                                                      unsigned short* __restrict__ x0bf) {
    long t = (long)blockIdx.x * 256 + threadIdx.x;
    int isf = *flagF;
    if (t < (long)N_NODES * IN_CH) x0bf[t] = ldbf(x0, t, isf);
}

// ---------------- weight prep ----------------
__global__ void prep_kernel(const void* __restrict__ w1r, const void* __restrict__ w1x,
                            const void* __restrict__ w2r, const void* __restrict__ w2x,
                            const void* __restrict__ lw,
                            const void* __restrict__ b1h, const void* __restrict__ b2h,
                            const void* __restrict__ lbh, const int* __restrict__ flagF,
                            unsigned short* __restrict__ Bt1, unsigned short* __restrict__ Bt2,
                            unsigned short* __restrict__ Bt3,
                            float* __restrict__ b1, float* __restrict__ b2, float* __restrict__ b3) {
    int isf = *flagF;
    int t = blockIdx.x * 256 + threadIdx.x;
    if (t < 256 * 256) {
        int n = t >> 8, k = t & 255;
        Bt1[n * 256 + k] = (k < 128) ? ldbf(w1r, k * 256 + n, isf) : ldbf(w1x, (k - 128) * 256 + n, isf);
        return;
    }
    t -= 256 * 256;
    if (t < 256 * 512) {
        int n = t >> 9, k = t & 511;
        Bt2[n * 512 + k] = (k < 256) ? ldbf(w2r, k * 256 + n, isf) : ldbf(w2x, (k - 256) * 256 + n, isf);
        return;
    }
    t -= 256 * 512;
    if (t < 64 * 512) {
        int n = t >> 9, k = t & 511;
        Bt3[n * 512 + k] = (n < OUTC) ? ldbf(lw, k * OUTC + n, isf) : (unsigned short)0;
        return;
    }
    t -= 64 * 512;
    if (t < 256) { b1[t] = ldf(b1h, t, isf); return; }
    t -= 256;
    if (t < 256) { b2[t] = ldf(b2h, t, isf); return; }
    t -= 256;
    if (t < 64)  { b3[t] = (t < OUTC) ? ldf(lbh, t, isf) : 0.0f; return; }
}

// ---------------- CSR: histogram ----------------
__global__ __launch_bounds__(256) void hist_kernel(const int* __restrict__ ei, const int* __restrict__ flagI,
                                                   int* __restrict__ cnt) {
    int e = blockIdx.x * 256 + threadIdx.x;
    if (e >= N_EDGES) return;
    int is64 = (*flagI == 0);
    int src, dst; load_edge(ei, e, is64, &src, &dst);
    if ((unsigned)src >= N_NODES || (unsigned)dst >= N_NODES) return;
    atomicAdd(&cnt[dst], 1);
}

// ---------------- 3-phase exclusive scan ----------------
__global__ __launch_bounds__(256) void scanA_kernel(const int* __restrict__ cnt, int* __restrict__ rp,
                                                    int* __restrict__ bsum) {
    __shared__ int sd[256];
    int tid = threadIdx.x;
    int i = blockIdx.x * 256 + tid;
    int v = (i < N_NODES) ? cnt[i] : 0;
    sd[tid] = v;
    __syncthreads();
    for (int off = 1; off < 256; off <<= 1) {
        int t = (tid >= off) ? sd[tid - off] : 0;
        __syncthreads();
        sd[tid] += t;
        __syncthreads();
    }
    if (i < N_NODES) rp[i] = sd[tid] - v;
    if (tid == 255) bsum[blockIdx.x] = sd[255];
}
__global__ __launch_bounds__(256) void scanB_kernel(int* __restrict__ bsum, int nB, int* __restrict__ rpN) {
    __shared__ int sd[256];
    int tid = threadIdx.x;
    int v = (tid < nB) ? bsum[tid] : 0;
    sd[tid] = v;
    __syncthreads();
    for (int off = 1; off < 256; off <<= 1) {
        int t = (tid >= off) ? sd[tid - off] : 0;
        __syncthreads();
        sd[tid] += t;
        __syncthreads();
    }
    if (tid < nB) bsum[tid] = sd[tid] - v;
    if (tid == 255) *rpN = sd[255];
}
__global__ __launch_bounds__(256) void scanC_kernel(int* __restrict__ rp, const int* __restrict__ bsum,
                                                    int* __restrict__ cursor) {
    int i = blockIdx.x * 256 + threadIdx.x;
    if (i < N_NODES) {
        int v = rp[i] + bsum[blockIdx.x];
        rp[i] = v;
        cursor[i] = v;
    }
}

// ---------------- CSR: fill (converts weight to bf16 inline) ----------------
__global__ __launch_bounds__(256) void fill_kernel(const int* __restrict__ ei, const void* __restrict__ ew,
                                                   const int* __restrict__ flagI, const int* __restrict__ flagF,
                                                   int* __restrict__ cursor,
                                                   int* __restrict__ col, unsigned short* __restrict__ wgt) {
    int e = blockIdx.x * 256 + threadIdx.x;
    if (e >= N_EDGES) return;
    int is64 = (*flagI == 0);
    int src, dst; load_edge(ei, e, is64, &src, &dst);
    if ((unsigned)src >= N_NODES || (unsigned)dst >= N_NODES) return;
    int pos = atomicAdd(&cursor[dst], 1);
    if ((unsigned)pos < N_EDGES) { col[pos] = src; wgt[pos] = ldbf(ew, e, *flagF); }
}

// ---------------- fallback: zero output ----------------
__global__ __launch_bounds__(256) void zout_kernel(unsigned short* __restrict__ out, long n) {
    long t = (long)blockIdx.x * 256 + threadIdx.x;
    if (t < n) out[t] = 0;
}

// ---------------- agg1: X12[r][256+c] = bf16(sum_j w_j * x0[col_j][c]), c<128 ----------------
__global__ __launch_bounds__(256) void agg1_kernel(const unsigned short* __restrict__ x0b,
                                                   const int* __restrict__ rp, const int* __restrict__ col,
                                                   const unsigned short* __restrict__ wgt,
                                                   unsigned short* __restrict__ X12) {
    int r = blockIdx.x * 4 + (threadIdx.x >> 6);
    if (r >= N_NODES) return;
    int lane = threadIdx.x & 63;
    int js = rp[r], je = rp[r + 1];
    if (js < 0) js = 0;
    if (je > N_EDGES) je = N_EDGES;
    const unsigned int* xw = (const unsigned int*)x0b;  // 64 uints per row
    float a0 = 0.f, a1 = 0.f;
    int j = js;
    for (; j + 4 <= je; j += 4) {
        int s0 = col[j], s1 = col[j+1], s2 = col[j+2], s3 = col[j+3];
        float w0 = bf2f(wgt[j]),   w1 = bf2f(wgt[j+1]);
        float w2 = bf2f(wgt[j+2]), w3 = bf2f(wgt[j+3]);
        unsigned int p0 = xw[(long)s0 * 64 + lane];
        unsigned int p1 = xw[(long)s1 * 64 + lane];
        unsigned int p2 = xw[(long)s2 * 64 + lane];
        unsigned int p3 = xw[(long)s3 * 64 + lane];
        a0 += w0 * bf2f((unsigned short)p0) + w1 * bf2f((unsigned short)p1)
            + w2 * bf2f((unsigned short)p2) + w3 * bf2f((unsigned short)p3);
        a1 += w0 * bf2f((unsigned short)(p0 >> 16)) + w1 * bf2f((unsigned short)(p1 >> 16))
            + w2 * bf2f((unsigned short)(p2 >> 16)) + w3 * bf2f((unsigned short)(p3 >> 16));
    }
    for (; j < je; j++) {
        int s0 = col[j];
        float w0 = bf2f(wgt[j]);
        unsigned int p0 = xw[(long)s0 * 64 + lane];
        a0 += w0 * bf2f((unsigned short)p0);
        a1 += w0 * bf2f((unsigned short)(p0 >> 16));
    }
    unsigned int pk = (unsigned int)f2bf(a0) | ((unsigned int)f2bf(a1) << 16);
    *(unsigned int*)&X12[(long)r * 512 + 256 + lane * 2] = pk;
}

// ---------------- agg2: X12[r][256+c] = bf16(sum_j w_j * x1[col_j][c]), c<256 ----------------
__global__ __launch_bounds__(256) void agg2_kernel(const int* __restrict__ rp, const int* __restrict__ col,
                                                   const unsigned short* __restrict__ wgt,
                                                   unsigned short* __restrict__ X12) {
    int r = blockIdx.x * 4 + (threadIdx.x >> 6);
    if (r >= N_NODES) return;
    int lane = threadIdx.x & 63;
    int js = rp[r], je = rp[r + 1];
    if (js < 0) js = 0;
    if (je > N_EDGES) je = N_EDGES;
    float a0 = 0.f, a1 = 0.f, a2 = 0.f, a3 = 0.f;
    int j = js;
    for (; j + 4 <= je; j += 4) {
        int s0 = col[j], s1 = col[j+1], s2 = col[j+2], s3 = col[j+3];
        float w0 = bf2f(wgt[j]),   w1 = bf2f(wgt[j+1]);
        float w2 = bf2f(wgt[j+2]), w3 = bf2f(wgt[j+3]);
        ushort4 q0 = *(const ushort4*)(X12 + (long)s0 * 512 + lane * 4);
        ushort4 q1 = *(const ushort4*)(X12 + (long)s1 * 512 + lane * 4);
        ushort4 q2 = *(const ushort4*)(X12 + (long)s2 * 512 + lane * 4);
        ushort4 q3 = *(const ushort4*)(X12 + (long)s3 * 512 + lane * 4);
        a0 += w0 * bf2f(q0.x) + w1 * bf2f(q1.x) + w2 * bf2f(q2.x) + w3 * bf2f(q3.x);
        a1 += w0 * bf2f(q0.y) + w1 * bf2f(q1.y) + w2 * bf2f(q2.y) + w3 * bf2f(q3.y);
        a2 += w0 * bf2f(q0.z) + w1 * bf2f(q1.z) + w2 * bf2f(q2.z) + w3 * bf2f(q3.z);
        a3 += w0 * bf2f(q0.w) + w1 * bf2f(q1.w) + w2 * bf2f(q2.w) + w3 * bf2f(q3.w);
    }
    for (; j < je; j++) {
        int s0 = col[j];
        float w0 = bf2f(wgt[j]);
        ushort4 q0 = *(const ushort4*)(X12 + (long)s0 * 512 + lane * 4);
        a0 += w0 * bf2f(q0.x); a1 += w0 * bf2f(q0.y);
        a2 += w0 * bf2f(q0.z); a3 += w0 * bf2f(q0.w);
    }
    uint2 pk;
    pk.x = (unsigned int)f2bf(a0) | ((unsigned int)f2bf(a1) << 16);
    pk.y = (unsigned int)f2bf(a2) | ((unsigned int)f2bf(a3) << 16);
    *(uint2*)&X12[(long)r * 512 + 256 + lane * 4] = pk;
}

// ---------------- MFMA GEMM, full-width (grid y=1) -------------------
template<int TN>
__global__ __launch_bounds__(256) void gemm_kernel(
    const unsigned short* __restrict__ Aagg, int lda_agg, int Kagg,
    const unsigned short* __restrict__ Ax, int lda_x,
    const unsigned short* __restrict__ Bt, int K,
    const float* __restrict__ bias,
    void* __restrict__ out, int ldo, int ocol,
    int M, int realN, int do_relu, const int* __restrict__ flagF, int follow_dtype) {
    __shared__ __align__(16) unsigned short As[64][72];
    __shared__ __align__(16) unsigned short Bs[TN * 32][72];
    int tid = threadIdx.x;
    int bm0 = blockIdx.x * 64;
    int wave = tid >> 6, lane = tid & 63;
    int wm = wave >> 1, wn = wave & 1;
    int quad = lane >> 4, l16 = lane & 15;

    f32x4 acc[2][TN];
#pragma unroll
    for (int mt = 0; mt < 2; mt++)
#pragma unroll
        for (int nt = 0; nt < TN; nt++) acc[mt][nt] = (f32x4){0.f, 0.f, 0.f, 0.f};

    for (int k0 = 0; k0 < K; k0 += 64) {
        const unsigned short* srcp;
        int stride, koff;
        if (k0 < Kagg) { srcp = Aagg; stride = lda_agg; koff = k0; }
        else           { srcp = Ax;   stride = lda_x;   koff = k0 - Kagg; }
#pragma unroll
        for (int i = 0; i < 2; i++) {
            int c = tid + i * 256;
            int row = c >> 3, ko = (c & 7) * 8;
            int gr = bm0 + row;
            if (gr >= M) gr = M - 1;  // clamp: dup rows, writes guarded
            u32x4 v = *(const u32x4*)(srcp + (long)gr * stride + koff + ko);
            *(u32x4*)&As[row][ko] = v;
        }
#pragma unroll
        for (int p = 0; p < TN; p++) {
            int c = p * 256 + tid;
            int row = c >> 3, ko = (c & 7) * 8;
            u32x4 v = *(const u32x4*)(Bt + (long)row * K + k0 + ko);
            *(u32x4*)&Bs[row][ko] = v;
        }
        __syncthreads();
#pragma unroll
        for (int kc = 0; kc < 64; kc += 32) {
            bf16x8 a0 = *(const bf16x8*)&As[wm * 32 + l16][kc + quad * 8];
            bf16x8 a1 = *(const bf16x8*)&As[wm * 32 + 16 + l16][kc + quad * 8];
#pragma unroll
            for (int nt = 0; nt < TN; nt++) {
                bf16x8 b = *(const bf16x8*)&Bs[wn * (TN * 16) + nt * 16 + l16][kc + quad * 8];
                acc[0][nt] = __builtin_amdgcn_mfma_f32_16x16x32_bf16(a0, b, acc[0][nt], 0, 0, 0);
                acc[1][nt] = __builtin_amdgcn_mfma_f32_16x16x32_bf16(a1, b, acc[1][nt], 0, 0, 0);
            }
        }
        __syncthreads();
    }

    int out_f32 = follow_dtype ? (*flagF) : 0;
#pragma unroll
    for (int mt = 0; mt < 2; mt++) {
#pragma unroll
        for (int nt = 0; nt < TN; nt++) {
            f32x4 a = acc[mt][nt];
            int colI = wn * (TN * 16) + nt * 16 + l16;
            float bv = bias[colI];
#pragma unroll
            for (int r = 0; r < 4; r++) {
                int row = bm0 + wm * 32 + mt * 16 + quad * 4 + r;
                if (row < M && colI < realN) {
                    float v = a[r] + bv;
                    if (do_relu) v = v > 0.f ? v : 0.f;
                    long idx = (long)row * ldo + ocol + colI;
                    if (out_f32) ((float*)out)[idx] = v;
                    else ((unsigned short*)out)[idx] = f2bf(v);
                }
            }
        }
    }
}

extern "C" void kernel_launch(void* const* d_in, const int* in_sizes, int n_in,
                              void* d_out, int out_size, void* d_ws, size_t ws_size,
                              hipStream_t stream) {
    const void* x0  = d_in[0];
    const int*  ei  = (const int*)d_in[1];
    const void* ew  = d_in[2];
    const void* w1r = d_in[3];
    const void* b1h = d_in[4];
    const void* w1x = d_in[5];
    const void* w2r = d_in[6];
    const void* b2h = d_in[7];
    const void* w2x = d_in[8];
    const void* lw  = d_in[9];
    const void* lbh = d_in[10];

    // ---- workspace layout ----
    char* ws = (char*)d_ws;
    unsigned short* X12     = (unsigned short*)(ws);             // 51,200,000  [N x 512]
    int*            colA    = (int*)(ws + 51200000);             //  3,200,000
    unsigned short* wgtA    = (unsigned short*)(ws + 54400000);  //  1,600,000
    int*            row_ptr = (int*)(ws + 56000000);             //    200,064
    int*            cursor  = (int*)(ws + 56200064);             //    200,064
    unsigned short* Bt1     = (unsigned short*)(ws + 56400128);  //    131,072
    unsigned short* Bt2     = (unsigned short*)(ws + 56531200);  //    262,144
    unsigned short* Bt3     = (unsigned short*)(ws + 56793344);  //     65,536
    float*          b1      = (float*)(ws + 56858880);           //      1,024
    float*          b2      = (float*)(ws + 56859904);           //      1,024
    float*          b3      = (float*)(ws + 56860928);           //        256
    int*            flags   = (int*)(ws + 56861184);             //         64
    int*            bsum    = (int*)(ws + 56861248);             //      1,024
    unsigned short* x0bf    = (unsigned short*)(ws + 56862272);  // 12,800,000
    const size_t NEED_FULL   = 69662272;
    const size_t NEED_NOCONV = 56862272;

    if (ws_size < NEED_NOCONV) {
        long n = (long)N_NODES * OUTC;
        zout_kernel<<<(int)((n + 255) / 256), 256, 0, stream>>>((unsigned short*)d_out, n);
        return;
    }
    int do_conv = (ws_size >= NEED_FULL) ? 1 : 0;

    int* flagF = flags + 0;
    int* flagI = flags + 1;

    zeroinit_kernel<<<(N_NODES + 3 + 255) / 256, 256, 0, stream>>>(cursor, flags);
    probe_kernel<<<1, 64, 0, stream>>>((const unsigned int*)x0, flagF);
    detect_kernel<<<1, 256, 0, stream>>>(ei, flagI);

    const unsigned short* x0b;
    if (do_conv) {
        long nconv = (long)N_NODES * IN_CH;
        convert_kernel<<<(int)((nconv + 255) / 256), 256, 0, stream>>>(x0, flagF, x0bf);
        x0b = x0bf;
    } else {
        x0b = (const unsigned short*)x0;
    }

    {
        int total = 256 * 256 + 256 * 512 + 64 * 512 + 256 + 256 + 64;
        prep_kernel<<<(total + 255) / 256, 256, 0, stream>>>(w1r, w1x, w2r, w2x, lw, b1h, b2h, lbh,
                                                             flagF, Bt1, Bt2, Bt3, b1, b2, b3);
    }

    // CSR build
    int eblocks = (N_EDGES + 255) / 256;
    int nblk = (N_NODES + 255) / 256;  // 196
    hist_kernel<<<eblocks, 256, 0, stream>>>(ei, flagI, cursor);
    scanA_kernel<<<nblk, 256, 0, stream>>>(cursor, row_ptr, bsum);
    scanB_kernel<<<1, 256, 0, stream>>>(bsum, nblk, &row_ptr[N_NODES]);
    scanC_kernel<<<nblk, 256, 0, stream>>>(row_ptr, bsum, cursor);
    fill_kernel<<<eblocks, 256, 0, stream>>>(ei, ew, flagI, flagF, cursor, colA, wgtA);

    int mblocks = (N_NODES + 63) / 64;  // 782
    int ablocks = (N_NODES + 3) / 4;    // 12500

    // layer 1: agg1 -> X12 cols 256..383; gemm1: [agg1|x0] @ Bt1 -> x1 (cols 0..255)
    agg1_kernel<<<ablocks, 256, 0, stream>>>(x0b, row_ptr, colA, wgtA, X12);
    gemm_kernel<8><<<dim3(mblocks, 1), 256, 0, stream>>>(X12 + 256, 512, 128,
                                                         x0b, IN_CH, Bt1, 256, b1,
                                                         X12, 512, 0, N_NODES, 256, 1, flagF, 0);
    // layer 2: agg2 -> X12 cols 256..511; gemm2: [agg2|x1] @ Bt2 -> x2 (cols 256..511, per-row overwrite)
    agg2_kernel<<<ablocks, 256, 0, stream>>>(row_ptr, colA, wgtA, X12);
    gemm_kernel<8><<<dim3(mblocks, 1), 256, 0, stream>>>(X12 + 256, 512, 256,
                                                         X12, 512, Bt2, 512, b2,
                                                         X12, 512, 256, N_NODES, 256, 1, flagF, 0);
    // head: [x1|x2] @ Bt3 -> out
    gemm_kernel<2><<<dim3(mblocks, 1), 256, 0, stream>>>(X12 + 256, 512, 0,
                                                         X12, 512, Bt3, 512, b3,
                                                         d_out, OUTC, 0, N_NODES, OUTC, 0, flagF, 1);
}

// Round 7
// 375.797 us; speedup vs baseline: 2.8393x; 1.0352x over previous
//
#include <hip/hip_runtime.h>
#include <hip/hip_bf16.h>

#define N_NODES 50000
#define N_EDGES 800000
#define IN_CH   128
#define HID     256
#define OUTC    51

typedef __attribute__((ext_vector_type(8))) short  bf16x8;
typedef __attribute__((ext_vector_type(4))) float  f32x4;
typedef __attribute__((ext_vector_type(4))) unsigned int u32x4;

__device__ __forceinline__ float bf2f(unsigned short u) {
    union { unsigned int i; float f; } v; v.i = ((unsigned int)u) << 16; return v.f;
}
__device__ __forceinline__ unsigned short f2bf(float f) {
    union { float f; unsigned int i; } v; v.f = f;
    unsigned int u = v.i;
    unsigned int r = (u + 0x7fffu + ((u >> 16) & 1u)) >> 16;  // RNE
    return (unsigned short)r;
}
__device__ __forceinline__ unsigned short ldbf(const void* p, long i, int isf) {
    return isf ? f2bf(((const float*)p)[i]) : ((const unsigned short*)p)[i];
}
__device__ __forceinline__ float ldf(const void* p, long i, int isf) {
    return isf ? ((const float*)p)[i] : bf2f(((const unsigned short*)p)[i]);
}
__device__ __forceinline__ void load_edge(const int* __restrict__ ei, int e, int is64,
                                          int* src, int* dst) {
    if (is64) { *src = ei[2 * e]; *dst = ei[2 * (N_EDGES + e)]; }
    else      { *src = ei[e];     *dst = ei[N_EDGES + e]; }
}

#define CURBLK 196  // blocks to zero cursor[50001]

// ---------------- init: zero cursor + dtype probe + int64 detect (one launch) ----------------
__global__ __launch_bounds__(256) void init_kernel(int* __restrict__ cursor,
                                                   const unsigned int* __restrict__ x0w, int* __restrict__ flagF,
                                                   const int* __restrict__ ei, int* __restrict__ flagI) {
    int b = blockIdx.x;
    int tid = threadIdx.x;
    if (b < CURBLK) {
        int t = b * 256 + tid;
        if (t < N_NODES + 1) cursor[t] = 0;
        return;
    }
    if (b == CURBLK) {
        // dtype probe: bf16 pairs have bits14..7 = exponent in [0x60,0x90] ~always; fp32 ~19%
        if (tid < 64) {
            unsigned int w = x0w[tid];
            unsigned int ex = (w >> 7) & 0xFFu;
            unsigned long long bm = __ballot(ex >= 0x60u && ex <= 0x90u);
            if (tid == 0) *flagF = (__popcll(bm) >= 48) ? 0 : 1;
        }
        return;
    }
    // int64 detect: 2048 strided samples of odd words; all-zero => int64
    __shared__ int any;
    if (tid == 0) any = 0;
    __syncthreads();
    int acc = 0;
    for (int s = 0; s < 8; s++) {
        int i = (tid * 8 + s) * (N_EDGES / 2048);
        acc |= ei[2 * i + 1];
    }
    if (acc != 0) any = 1;
    __syncthreads();
    if (tid == 0) *flagI = any;
}

// ---------------- prep_all: x0 convert (cb blocks) + weight prep (899 blocks) ----------------
__global__ void prep_all_kernel(const void* __restrict__ x0, int cb,
                                const void* __restrict__ w1r, const void* __restrict__ w1x,
                                const void* __restrict__ w2r, const void* __restrict__ w2x,
                                const void* __restrict__ lw,
                                const void* __restrict__ b1h, const void* __restrict__ b2h,
                                const void* __restrict__ lbh, const int* __restrict__ flagF,
                                unsigned short* __restrict__ x0bf,
                                unsigned short* __restrict__ Bt1, unsigned short* __restrict__ Bt2,
                                unsigned short* __restrict__ Bt3,
                                float* __restrict__ b1, float* __restrict__ b2, float* __restrict__ b3) {
    int isf = *flagF;
    if ((int)blockIdx.x < cb) {
        long t = (long)blockIdx.x * 256 + threadIdx.x;
        if (t < (long)N_NODES * IN_CH) x0bf[t] = ldbf(x0, t, isf);
        return;
    }
    int t = (blockIdx.x - cb) * 256 + threadIdx.x;
    if (t < 256 * 256) {
        int n = t >> 8, k = t & 255;
        Bt1[n * 256 + k] = (k < 128) ? ldbf(w1r, k * 256 + n, isf) : ldbf(w1x, (k - 128) * 256 + n, isf);
        return;
    }
    t -= 256 * 256;
    if (t < 256 * 512) {
        int n = t >> 9, k = t & 511;
        Bt2[n * 512 + k] = (k < 256) ? ldbf(w2r, k * 256 + n, isf) : ldbf(w2x, (k - 256) * 256 + n, isf);
        return;
    }
    t -= 256 * 512;
    if (t < 64 * 512) {
        int n = t >> 9, k = t & 511;
        Bt3[n * 512 + k] = (n < OUTC) ? ldbf(lw, k * OUTC + n, isf) : (unsigned short)0;
        return;
    }
    t -= 64 * 512;
    if (t < 256) { b1[t] = ldf(b1h, t, isf); return; }
    t -= 256;
    if (t < 256) { b2[t] = ldf(b2h, t, isf); return; }
    t -= 256;
    if (t < 64)  { b3[t] = (t < OUTC) ? ldf(lbh, t, isf) : 0.0f; return; }
}

// ---------------- CSR: histogram ----------------
__global__ __launch_bounds__(256) void hist_kernel(const int* __restrict__ ei, const int* __restrict__ flagI,
                                                   int* __restrict__ cnt) {
    int e = blockIdx.x * 256 + threadIdx.x;
    if (e >= N_EDGES) return;
    int is64 = (*flagI == 0);
    int src, dst; load_edge(ei, e, is64, &src, &dst);
    if ((unsigned)src >= N_NODES || (unsigned)dst >= N_NODES) return;
    atomicAdd(&cnt[dst], 1);
}

// ---------------- scan phase A: per-block exclusive + block sums ----------------
__global__ __launch_bounds__(256) void scanA_kernel(const int* __restrict__ cnt, int* __restrict__ rp,
                                                    int* __restrict__ bsum) {
    __shared__ int sd[256];
    int tid = threadIdx.x;
    int i = blockIdx.x * 256 + tid;
    int v = (i < N_NODES) ? cnt[i] : 0;
    sd[tid] = v;
    __syncthreads();
    for (int off = 1; off < 256; off <<= 1) {
        int t = (tid >= off) ? sd[tid - off] : 0;
        __syncthreads();
        sd[tid] += t;
        __syncthreads();
    }
    if (i < N_NODES) rp[i] = sd[tid] - v;
    if (tid == 255) bsum[blockIdx.x] = sd[255];
}
// ---------------- scan phase C: each block re-scans bsum locally, applies prefix ----------------
__global__ __launch_bounds__(256) void scanC_kernel(int* __restrict__ rp, const int* __restrict__ bsum,
                                                    int* __restrict__ cursor, int nB) {
    __shared__ int sd[256];
    int tid = threadIdx.x;
    int v = (tid < nB) ? bsum[tid] : 0;
    sd[tid] = v;
    __syncthreads();
    for (int off = 1; off < 256; off <<= 1) {
        int t = (tid >= off) ? sd[tid - off] : 0;
        __syncthreads();
        sd[tid] += t;
        __syncthreads();
    }
    int pfx = (blockIdx.x > 0) ? sd[blockIdx.x - 1] : 0;
    int i = blockIdx.x * 256 + tid;
    if (i < N_NODES) {
        int val = rp[i] + pfx;
        rp[i] = val;
        cursor[i] = val;
    }
    if (blockIdx.x == 0 && tid == 0) rp[N_NODES] = sd[255];
}

// ---------------- CSR: fill (weight converted to bf16 inline) ----------------
__global__ __launch_bounds__(256) void fill_kernel(const int* __restrict__ ei, const void* __restrict__ ew,
                                                   const int* __restrict__ flagI, const int* __restrict__ flagF,
                                                   int* __restrict__ cursor,
                                                   int* __restrict__ col, unsigned short* __restrict__ wgt) {
    int e = blockIdx.x * 256 + threadIdx.x;
    if (e >= N_EDGES) return;
    int is64 = (*flagI == 0);
    int src, dst; load_edge(ei, e, is64, &src, &dst);
    if ((unsigned)src >= N_NODES || (unsigned)dst >= N_NODES) return;
    int pos = atomicAdd(&cursor[dst], 1);
    if ((unsigned)pos < N_EDGES) { col[pos] = src; wgt[pos] = ldbf(ew, e, *flagF); }
}

// ---------------- fallback: zero output ----------------
__global__ __launch_bounds__(256) void zout_kernel(unsigned short* __restrict__ out, long n) {
    long t = (long)blockIdx.x * 256 + threadIdx.x;
    if (t < n) out[t] = 0;
}

// ---------------- agg1: X12[r][256+c] = bf16(sum_j w_j * x0[col_j][c]), c<128 ----------------
// one wave/node; cooperative col/wgt preload + shfl broadcast; 8 row-loads in flight
__global__ __launch_bounds__(256) void agg1_kernel(const unsigned short* __restrict__ x0b,
                                                   const int* __restrict__ rp, const int* __restrict__ col,
                                                   const unsigned short* __restrict__ wgt,
                                                   unsigned short* __restrict__ X12) {
    int r = blockIdx.x * 4 + (threadIdx.x >> 6);
    if (r >= N_NODES) return;
    int lane = threadIdx.x & 63;
    int js = rp[r], je = rp[r + 1];
    if (js < 0) js = 0;
    if (je > N_EDGES) je = N_EDGES;
    const unsigned int* xw = (const unsigned int*)x0b;  // 64 uints per row
    float a0 = 0.f, a1 = 0.f;
    for (int base = js; base < je; base += 64) {
        int n = je - base; if (n > 64) n = 64;
        int idx = base + lane; if (idx >= N_EDGES) idx = N_EDGES - 1;
        int cc = col[idx];
        float ww = bf2f(wgt[idx]);
        for (int j = 0; j < n; j += 8) {
            int m = n - j; if (m > 8) m = 8;
            unsigned int q[8];
            int ss[8];
#pragma unroll
            for (int u = 0; u < 8; u++) ss[u] = __shfl(cc, j + u);
#pragma unroll
            for (int u = 0; u < 8; u++) if (u < m) q[u] = xw[(long)ss[u] * 64 + lane];
#pragma unroll
            for (int u = 0; u < 8; u++) if (u < m) {
                float w = __shfl(ww, j + u);
                a0 += w * bf2f((unsigned short)(q[u] & 0xffffu));
                a1 += w * bf2f((unsigned short)(q[u] >> 16));
            }
        }
    }
    unsigned int pk = (unsigned int)f2bf(a0) | ((unsigned int)f2bf(a1) << 16);
    *(unsigned int*)&X12[(long)r * 512 + 256 + lane * 2] = pk;
}

// ---------------- agg2: X12[r][256+c] = bf16(sum_j w_j * x1[col_j][c]), c<256 ----------------
__global__ __launch_bounds__(256) void agg2_kernel(const int* __restrict__ rp, const int* __restrict__ col,
                                                   const unsigned short* __restrict__ wgt,
                                                   unsigned short* __restrict__ X12) {
    int r = blockIdx.x * 4 + (threadIdx.x >> 6);
    if (r >= N_NODES) return;
    int lane = threadIdx.x & 63;
    int js = rp[r], je = rp[r + 1];
    if (js < 0) js = 0;
    if (je > N_EDGES) je = N_EDGES;
    float a0 = 0.f, a1 = 0.f, a2 = 0.f, a3 = 0.f;
    for (int base = js; base < je; base += 64) {
        int n = je - base; if (n > 64) n = 64;
        int idx = base + lane; if (idx >= N_EDGES) idx = N_EDGES - 1;
        int cc = col[idx];
        float ww = bf2f(wgt[idx]);
        for (int j = 0; j < n; j += 8) {
            int m = n - j; if (m > 8) m = 8;
            uint2 q[8];
            int ss[8];
#pragma unroll
            for (int u = 0; u < 8; u++) ss[u] = __shfl(cc, j + u);
#pragma unroll
            for (int u = 0; u < 8; u++) if (u < m)
                q[u] = *(const uint2*)(X12 + (long)ss[u] * 512 + lane * 4);
#pragma unroll
            for (int u = 0; u < 8; u++) if (u < m) {
                float w = __shfl(ww, j + u);
                a0 += w * bf2f((unsigned short)(q[u].x & 0xffffu));
                a1 += w * bf2f((unsigned short)(q[u].x >> 16));
                a2 += w * bf2f((unsigned short)(q[u].y & 0xffffu));
                a3 += w * bf2f((unsigned short)(q[u].y >> 16));
            }
        }
    }
    uint2 pk;
    pk.x = (unsigned int)f2bf(a0) | ((unsigned int)f2bf(a1) << 16);
    pk.y = (unsigned int)f2bf(a2) | ((unsigned int)f2bf(a3) << 16);
    *(uint2*)&X12[(long)r * 512 + 256 + lane * 4] = pk;
}

// ---------------- MFMA GEMM, full-width (grid y=1) -------------------
template<int TN>
__global__ __launch_bounds__(256) void gemm_kernel(
    const unsigned short* __restrict__ Aagg, int lda_agg, int Kagg,
    const unsigned short* __restrict__ Ax, int lda_x,
    const unsigned short* __restrict__ Bt, int K,
    const float* __restrict__ bias,
    void* __restrict__ out, int ldo, int ocol,
    int M, int realN, int do_relu, const int* __restrict__ flagF, int follow_dtype) {
    __shared__ __align__(16) unsigned short As[64][72];
    __shared__ __align__(16) unsigned short Bs[TN * 32][72];
    int tid = threadIdx.x;
    int bm0 = blockIdx.x * 64;
    int wave = tid >> 6, lane = tid & 63;
    int wm = wave >> 1, wn = wave & 1;
    int quad = lane >> 4, l16 = lane & 15;

    f32x4 acc[2][TN];
#pragma unroll
    for (int mt = 0; mt < 2; mt++)
#pragma unroll
        for (int nt = 0; nt < TN; nt++) acc[mt][nt] = (f32x4){0.f, 0.f, 0.f, 0.f};

    for (int k0 = 0; k0 < K; k0 += 64) {
        const unsigned short* srcp;
        int stride, koff;
        if (k0 < Kagg) { srcp = Aagg; stride = lda_agg; koff = k0; }
        else           { srcp = Ax;   stride = lda_x;   koff = k0 - Kagg; }
#pragma unroll
        for (int i = 0; i < 2; i++) {
            int c = tid + i * 256;
            int row = c >> 3, ko = (c & 7) * 8;
            int gr = bm0 + row;
            if (gr >= M) gr = M - 1;  // clamp: dup rows, writes guarded
            u32x4 v = *(const u32x4*)(srcp + (long)gr * stride + koff + ko);
            *(u32x4*)&As[row][ko] = v;
        }
#pragma unroll
        for (int p = 0; p < TN; p++) {
            int c = p * 256 + tid;
            int row = c >> 3, ko = (c & 7) * 8;
            u32x4 v = *(const u32x4*)(Bt + (long)row * K + k0 + ko);
            *(u32x4*)&Bs[row][ko] = v;
        }
        __syncthreads();
#pragma unroll
        for (int kc = 0; kc < 64; kc += 32) {
            bf16x8 a0 = *(const bf16x8*)&As[wm * 32 + l16][kc + quad * 8];
            bf16x8 a1 = *(const bf16x8*)&As[wm * 32 + 16 + l16][kc + quad * 8];
#pragma unroll
            for (int nt = 0; nt < TN; nt++) {
                bf16x8 b = *(const bf16x8*)&Bs[wn * (TN * 16) + nt * 16 + l16][kc + quad * 8];
                acc[0][nt] = __builtin_amdgcn_mfma_f32_16x16x32_bf16(a0, b, acc[0][nt], 0, 0, 0);
                acc[1][nt] = __builtin_amdgcn_mfma_f32_16x16x32_bf16(a1, b, acc[1][nt], 0, 0, 0);
            }
        }
        __syncthreads();
    }

    int out_f32 = follow_dtype ? (*flagF) : 0;
#pragma unroll
    for (int mt = 0; mt < 2; mt++) {
#pragma unroll
        for (int nt = 0; nt < TN; nt++) {
            f32x4 a = acc[mt][nt];
            int colI = wn * (TN * 16) + nt * 16 + l16;
            float bv = bias[colI];
#pragma unroll
            for (int r = 0; r < 4; r++) {
                int row = bm0 + wm * 32 + mt * 16 + quad * 4 + r;
                if (row < M && colI < realN) {
                    float v = a[r] + bv;
                    if (do_relu) v = v > 0.f ? v : 0.f;
                    long idx = (long)row * ldo + ocol + colI;
                    if (out_f32) ((float*)out)[idx] = v;
                    else ((unsigned short*)out)[idx] = f2bf(v);
                }
            }
        }
    }
}

extern "C" void kernel_launch(void* const* d_in, const int* in_sizes, int n_in,
                              void* d_out, int out_size, void* d_ws, size_t ws_size,
                              hipStream_t stream) {
    const void* x0  = d_in[0];
    const int*  ei  = (const int*)d_in[1];
    const void* ew  = d_in[2];
    const void* w1r = d_in[3];
    const void* b1h = d_in[4];
    const void* w1x = d_in[5];
    const void* w2r = d_in[6];
    const void* b2h = d_in[7];
    const void* w2x = d_in[8];
    const void* lw  = d_in[9];
    const void* lbh = d_in[10];

    // ---- workspace layout ----
    char* ws = (char*)d_ws;
    unsigned short* X12     = (unsigned short*)(ws);             // 51,200,000  [N x 512]
    int*            colA    = (int*)(ws + 51200000);             //  3,200,000
    unsigned short* wgtA    = (unsigned short*)(ws + 54400000);  //  1,600,000
    int*            row_ptr = (int*)(ws + 56000000);             //    200,064
    int*            cursor  = (int*)(ws + 56200064);             //    200,064
    unsigned short* Bt1     = (unsigned short*)(ws + 56400128);  //    131,072
    unsigned short* Bt2     = (unsigned short*)(ws + 56531200);  //    262,144
    unsigned short* Bt3     = (unsigned short*)(ws + 56793344);  //     65,536
    float*          b1      = (float*)(ws + 56858880);           //      1,024
    float*          b2      = (float*)(ws + 56859904);           //      1,024
    float*          b3      = (float*)(ws + 56860928);           //        256
    int*            flags   = (int*)(ws + 56861184);             //         64
    int*            bsum    = (int*)(ws + 56861248);             //      1,024
    unsigned short* x0bf    = (unsigned short*)(ws + 56862272);  // 12,800,000
    const size_t NEED_FULL   = 69662272;
    const size_t NEED_NOCONV = 56862272;

    if (ws_size < NEED_NOCONV) {
        long n = (long)N_NODES * OUTC;
        zout_kernel<<<(int)((n + 255) / 256), 256, 0, stream>>>((unsigned short*)d_out, n);
        return;
    }
    int do_conv = (ws_size >= NEED_FULL) ? 1 : 0;

    int* flagF = flags + 0;
    int* flagI = flags + 1;

    // init: cursor zero (blocks 0..195) + probe (196) + detect (197)
    init_kernel<<<CURBLK + 2, 256, 0, stream>>>(cursor, (const unsigned int*)x0, flagF, ei, flagI);

    // convert + weight prep in one launch
    int cb = do_conv ? ((N_NODES * IN_CH + 255) / 256) : 0;  // 25000
    const unsigned short* x0b = do_conv ? x0bf : (const unsigned short*)x0;
    {
        int ptotal = 256 * 256 + 256 * 512 + 64 * 512 + 256 + 256 + 64;
        int pblocks = (ptotal + 255) / 256;  // 899
        prep_all_kernel<<<cb + pblocks, 256, 0, stream>>>(x0, cb, w1r, w1x, w2r, w2x, lw,
                                                          b1h, b2h, lbh, flagF, x0bf,
                                                          Bt1, Bt2, Bt3, b1, b2, b3);
    }

    // CSR build
    int eblocks = (N_EDGES + 255) / 256;
    int nblk = (N_NODES + 255) / 256;  // 196
    hist_kernel<<<eblocks, 256, 0, stream>>>(ei, flagI, cursor);
    scanA_kernel<<<nblk, 256, 0, stream>>>(cursor, row_ptr, bsum);
    scanC_kernel<<<nblk, 256, 0, stream>>>(row_ptr, bsum, cursor, nblk);
    fill_kernel<<<eblocks, 256, 0, stream>>>(ei, ew, flagI, flagF, cursor, colA, wgtA);

    int mblocks = (N_NODES + 63) / 64;  // 782
    int ablocks = (N_NODES + 3) / 4;    // 12500

    // layer 1: agg1 -> X12 cols 256..383; gemm1: [agg1|x0] @ Bt1 -> x1 (cols 0..255)
    agg1_kernel<<<ablocks, 256, 0, stream>>>(x0b, row_ptr, colA, wgtA, X12);
    gemm_kernel<8><<<dim3(mblocks, 1), 256, 0, stream>>>(X12 + 256, 512, 128,
                                                         x0b, IN_CH, Bt1, 256, b1,
                                                         X12, 512, 0, N_NODES, 256, 1, flagF, 0);
    // layer 2: agg2 -> X12 cols 256..511; gemm2: [agg2|x1] @ Bt2 -> x2 (cols 256..511, per-row overwrite)
    agg2_kernel<<<ablocks, 256, 0, stream>>>(row_ptr, colA, wgtA, X12);
    gemm_kernel<8><<<dim3(mblocks, 1), 256, 0, stream>>>(X12 + 256, 512, 256,
                                                         X12, 512, Bt2, 512, b2,
                                                         X12, 512, 256, N_NODES, 256, 1, flagF, 0);
    // head: [x1|x2] @ Bt3 -> out
    gemm_kernel<2><<<dim3(mblocks, 1), 256, 0, stream>>>(X12 + 256, 512, 0,
                                                         X12, 512, Bt3, 512, b3,
                                                         d_out, OUTC, 0, N_NODES, OUTC, 0, flagF, 1);
}